// Round 2
// baseline (60298.462 us; speedup 1.0000x reference)
//
#include <hip/hip_runtime.h>
#include <hip/hip_bf16.h>
#include <math.h>

typedef __hip_bfloat16 bf16;

constexpr int NB = 128;      // batch
constexpr int NT = 256;      // time
constexpr int HCAT = 1024;   // 512+256+256

// ---------------------------------------------------------------------------
// gx = x @ W_ih^T + b_ih + b_hh   (fp32 compute, bf16 store), time-chunked.
// Chunk-local row r = b*TC + tl  ->  x row = b*NT + t0 + tl.
// tile 64(rows) x 64(gate-rows), 256 threads, 4x4 microtile, K-chunk 32
// ---------------------------------------------------------------------------
__global__ __launch_bounds__(256) void k_gx(
    const float* __restrict__ x, const float* __restrict__ W,
    const float* __restrict__ bih, const float* __restrict__ bhh,
    bf16* __restrict__ gx, int d, int G, int t0, int tcShift)
{
  __shared__ float xs[32][68];
  __shared__ float ws_[32][68];
  const int bt0 = blockIdx.x * 64;
  const int r0  = blockIdx.y * 64;
  const int tid = threadIdx.x;
  const int tx = tid & 15;   // gate-row micro
  const int ty = tid >> 4;   // bt micro
  const int tcMask = (1 << tcShift) - 1;
  float acc[4][4];
#pragma unroll
  for (int p = 0; p < 4; ++p)
#pragma unroll
    for (int q = 0; q < 4; ++q) acc[p][q] = 0.f;

  for (int k0 = 0; k0 < d; k0 += 32) {
#pragma unroll
    for (int it = 0; it < 8; ++it) {
      int idx = tid + it * 256;
      int k = idx & 31, i = idx >> 5;
      int kk = k0 + k;
      int row = bt0 + i;
      int b = row >> tcShift, tl = row & tcMask;
      xs[k][i]  = (kk < d) ? x[((size_t)b * NT + t0 + tl) * d + kk] : 0.f;
      ws_[k][i] = (kk < d) ? W[(size_t)(r0 + i) * d + kk] : 0.f;
    }
    __syncthreads();
#pragma unroll 8
    for (int k = 0; k < 32; ++k) {
      float a[4], b[4];
#pragma unroll
      for (int p = 0; p < 4; ++p) a[p] = xs[k][ty * 4 + p];
#pragma unroll
      for (int q = 0; q < 4; ++q) b[q] = ws_[k][tx * 4 + q];
#pragma unroll
      for (int p = 0; p < 4; ++p)
#pragma unroll
        for (int q = 0; q < 4; ++q) acc[p][q] += a[p] * b[q];
    }
    __syncthreads();
  }
#pragma unroll
  for (int p = 0; p < 4; ++p) {
    int bt = bt0 + ty * 4 + p;
#pragma unroll
    for (int q = 0; q < 4; ++q) {
      int r = r0 + tx * 4 + q;
      float v = acc[p][q] + bih[r] + bhh[r];
      gx[(size_t)bt * G + r] = __float2bfloat16(v);
    }
  }
}

// ---------------------------------------------------------------------------
// fc1: Z = relu(A @ W1^T + b1)    A bf16 [rows,1024] (chunk), W fp32 [256,1024]
// ---------------------------------------------------------------------------
__global__ __launch_bounds__(256) void k_fc1(
    const bf16* __restrict__ A, const float* __restrict__ W,
    const float* __restrict__ bias, float* __restrict__ Z)
{
  __shared__ float xs[32][68];
  __shared__ float ws_[32][68];
  const int bt0 = blockIdx.x * 64;
  const int r0  = blockIdx.y * 64;
  const int tid = threadIdx.x;
  const int tx = tid & 15;
  const int ty = tid >> 4;
  float acc[4][4];
#pragma unroll
  for (int p = 0; p < 4; ++p)
#pragma unroll
    for (int q = 0; q < 4; ++q) acc[p][q] = 0.f;

  for (int k0 = 0; k0 < 1024; k0 += 32) {
#pragma unroll
    for (int it = 0; it < 8; ++it) {
      int idx = tid + it * 256;
      int k = idx & 31, i = idx >> 5;
      xs[k][i]  = __bfloat162float(A[(size_t)(bt0 + i) * 1024 + k0 + k]);
      ws_[k][i] = W[(size_t)(r0 + i) * 1024 + k0 + k];
    }
    __syncthreads();
#pragma unroll 8
    for (int k = 0; k < 32; ++k) {
      float a[4], b[4];
#pragma unroll
      for (int p = 0; p < 4; ++p) a[p] = xs[k][ty * 4 + p];
#pragma unroll
      for (int q = 0; q < 4; ++q) b[q] = ws_[k][tx * 4 + q];
#pragma unroll
      for (int p = 0; p < 4; ++p)
#pragma unroll
        for (int q = 0; q < 4; ++q) acc[p][q] += a[p] * b[q];
    }
    __syncthreads();
  }
#pragma unroll
  for (int p = 0; p < 4; ++p) {
    int bt = bt0 + ty * 4 + p;
#pragma unroll
    for (int q = 0; q < 4; ++q) {
      int r = r0 + tx * 4 + q;
      float v = acc[p][q] + bias[r];
      Z[(size_t)bt * 256 + r] = fmaxf(v, 0.f);
    }
  }
}

// ---------------------------------------------------------------------------
// fc2 + log_softmax: one wave per chunk row; map chunk row -> global (b,t)
// ---------------------------------------------------------------------------
__global__ __launch_bounds__(256) void k_fc2(
    const float* __restrict__ Z, const float* __restrict__ W2,
    const float* __restrict__ b2, float* __restrict__ out, int t0, int tcShift)
{
  const int wave = threadIdx.x >> 6;
  const int lane = threadIdx.x & 63;
  const int bt = blockIdx.x * 4 + wave;
  const float* z = Z + (size_t)bt * 256;
  float zv[4];
#pragma unroll
  for (int j = 0; j < 4; ++j) zv[j] = z[lane + 64 * j];
  float lg[7];
#pragma unroll
  for (int o = 0; o < 7; ++o) {
    float a = 0.f;
#pragma unroll
    for (int j = 0; j < 4; ++j) a += zv[j] * W2[o * 256 + lane + 64 * j];
#pragma unroll
    for (int off = 32; off > 0; off >>= 1) a += __shfl_down(a, off, 64);
    lg[o] = a;   // valid on lane 0
  }
  if (lane == 0) {
    const int b = bt >> tcShift;
    const int tl = bt & ((1 << tcShift) - 1);
    float* op = out + ((size_t)b * NT + t0 + tl) * 7;
    float lo[7];
    float m = -1e30f;
#pragma unroll
    for (int o = 0; o < 7; ++o) { lo[o] = lg[o] + b2[o]; m = fmaxf(m, lo[o]); }
    float s = 0.f;
#pragma unroll
    for (int o = 0; o < 7; ++o) s += expf(lo[o] - m);
    float lse = m + logf(s);
#pragma unroll
    for (int o = 0; o < 7; ++o) op[o] = lo[o] - lse;
  }
}

// ---------------------------------------------------------------------------
// Persistent recurrent kernel, chunked over time. 512 blocks (2/CU), 256 thr.
//   group g = blockIdx%8  -> batch rows [16g, 16g+16)
//   rank = blockIdx/8: 0..31 -> LSTM0 (16 units), 32..47 -> LSTM1, 48..63 -> LSTM2
// Barrier counter is monotone across chunks: target = 64*(t0+tl+1).
// h double-buffered in hbuf (fp32); chunk len even => h at buffer 0 on entry.
// c persisted per-column in cbuf.
// ---------------------------------------------------------------------------
__device__ inline void group_barrier(unsigned* ctr, unsigned target) {
  __syncthreads();
  if (threadIdx.x == 0) {
    __hip_atomic_fetch_add(ctr, 1u, __ATOMIC_RELEASE, __HIP_MEMORY_SCOPE_AGENT);
    while (__hip_atomic_load(ctr, __ATOMIC_ACQUIRE, __HIP_MEMORY_SCOPE_AGENT) < target) {
      __builtin_amdgcn_s_sleep(2);
    }
  }
  __syncthreads();
}

__global__ __launch_bounds__(256, 2) void k_lstm(
    const float* __restrict__ Whh0, const float* __restrict__ Whh1,
    const float* __restrict__ Whh2,
    const bf16* __restrict__ gx0, const bf16* __restrict__ gx1,
    const bf16* __restrict__ gx2,
    float* __restrict__ hbuf,           // [2][NB][HCAT]
    float* __restrict__ cbuf,           // [NB][HCAT]
    bf16* __restrict__ hs,              // [NB][TC][HCAT] chunk-local
    unsigned* __restrict__ bar,         // [8]
    int t0, int TC)
{
  const int g    = blockIdx.x & 7;
  const int rank = blockIdx.x >> 3;
  int l, ub;
  if (rank < 32)      { l = 0; ub = rank; }
  else if (rank < 48) { l = 1; ub = rank - 32; }
  else                { l = 2; ub = rank - 48; }
  const int Hl   = (l == 0) ? 512 : 256;
  const int hoff = (l == 0) ? 0 : ((l == 1) ? 512 : 768);
  const float* Whh = (l == 0) ? Whh0 : ((l == 1) ? Whh1 : Whh2);
  const bf16* gx   = (l == 0) ? gx0  : ((l == 1) ? gx1  : gx2);
  const int G4 = 4 * Hl;
  const int u0 = ub * 16;
  const int tid = threadIdx.x;
  const int u = tid & 15;        // unit within block
  const int b = tid >> 4;        // batch within group
  const int bb = g * 16 + b;
  const int hcol = hoff + u0 + u;

  const float* wr0 = Whh + (size_t)(0 * Hl + u0 + u) * Hl;
  const float* wr1 = Whh + (size_t)(1 * Hl + u0 + u) * Hl;
  const float* wr2 = Whh + (size_t)(2 * Hl + u0 + u) * Hl;
  const float* wr3 = Whh + (size_t)(3 * Hl + u0 + u) * Hl;

  float c = cbuf[(size_t)bb * HCAT + hcol];
  unsigned* ctr = bar + g;

  for (int t = 0; t < TC; ++t) {
    const float* hp = hbuf + ((size_t)(t & 1) * NB + bb) * HCAT + hoff;
    float a0 = 0.f, a1 = 0.f, a2 = 0.f, a3 = 0.f;
#pragma unroll 2
    for (int k = 0; k < Hl; k += 4) {
      float4 hv = *reinterpret_cast<const float4*>(hp + k);
      float4 w0 = *reinterpret_cast<const float4*>(wr0 + k);
      float4 w1 = *reinterpret_cast<const float4*>(wr1 + k);
      float4 w2 = *reinterpret_cast<const float4*>(wr2 + k);
      float4 w3 = *reinterpret_cast<const float4*>(wr3 + k);
      a0 += hv.x * w0.x + hv.y * w0.y + hv.z * w0.z + hv.w * w0.w;
      a1 += hv.x * w1.x + hv.y * w1.y + hv.z * w1.z + hv.w * w1.w;
      a2 += hv.x * w2.x + hv.y * w2.y + hv.z * w2.z + hv.w * w2.w;
      a3 += hv.x * w3.x + hv.y * w3.y + hv.z * w3.z + hv.w * w3.w;
    }
    const size_t gxb = ((size_t)bb * TC + t) * G4 + u0 + u;
    float pi = a0 + __bfloat162float(gx[gxb + 0 * (size_t)Hl]);
    float pf = a1 + __bfloat162float(gx[gxb + 1 * (size_t)Hl]);
    float pg = a2 + __bfloat162float(gx[gxb + 2 * (size_t)Hl]);
    float po = a3 + __bfloat162float(gx[gxb + 3 * (size_t)Hl]);
    float si = 1.f / (1.f + expf(-pi));
    float sf = 1.f / (1.f + expf(-pf));
    float so = 1.f / (1.f + expf(-po));
    float tg = tanhf(pg);
    c = sf * c + si * tg;
    float h = so * tanhf(c);
    hbuf[((size_t)((t + 1) & 1) * NB + bb) * HCAT + hcol] = h;
    hs[((size_t)bb * TC + t) * HCAT + hcol] = __float2bfloat16(h);
    group_barrier(ctr, 64u * (unsigned)(t0 + t + 1));
  }
  cbuf[(size_t)bb * HCAT + hcol] = c;
}

// fallback if workspace is too small: distinctive sentinel
__global__ void k_fill(float* __restrict__ out, int n, float v) {
  int i = blockIdx.x * 256 + threadIdx.x;
  if (i < n) out[i] = v;
}

extern "C" void kernel_launch(void* const* d_in, const int* in_sizes, int n_in,
                              void* d_out, int out_size, void* d_ws, size_t ws_size,
                              hipStream_t stream) {
  (void)in_sizes; (void)n_in;
  const float* x0  = (const float*)d_in[0];
  const float* x1  = (const float*)d_in[1];
  const float* x2  = (const float*)d_in[2];
  const float* Wih0 = (const float*)d_in[3];
  const float* Whh0 = (const float*)d_in[4];
  const float* bih0 = (const float*)d_in[5];
  const float* bhh0 = (const float*)d_in[6];
  const float* Wih1 = (const float*)d_in[7];
  const float* Whh1 = (const float*)d_in[8];
  const float* bih1 = (const float*)d_in[9];
  const float* bhh1 = (const float*)d_in[10];
  const float* Wih2 = (const float*)d_in[11];
  const float* Whh2 = (const float*)d_in[12];
  const float* bih2 = (const float*)d_in[13];
  const float* bhh2 = (const float*)d_in[14];
  const float* W1 = (const float*)d_in[15];
  const float* b1 = (const float*)d_in[16];
  const float* W2 = (const float*)d_in[17];
  const float* b2 = (const float*)d_in[18];
  float* out = (float*)d_out;

  // pick largest even chunk TC that fits in ws
  const int cands[6] = {256, 128, 64, 32, 16, 8};
  int TC = 0;
  for (int ci = 0; ci < 6; ++ci) {
    int tc = cands[ci];
    size_t rows = (size_t)NB * tc;
    size_t o = 0;
    auto al = [&](size_t bytes) { o += (bytes + 255) & ~(size_t)255; };
    al(64 * sizeof(unsigned));          // bar
    al((size_t)2 * NB * HCAT * 4);      // hbuf
    al((size_t)NB * HCAT * 4);          // cbuf
    al(rows * HCAT * 2);                // hs chunk
    al(rows * 256 * 4);                 // z chunk
    al(rows * 2048 * 2);                // gx0 chunk
    al(rows * 1024 * 2);                // gx1 chunk
    al(rows * 1024 * 2);                // gx2 chunk
    if (o <= ws_size) { TC = tc; break; }
  }
  if (TC == 0) {
    k_fill<<<dim3((out_size + 255) / 256), dim3(256), 0, stream>>>(out, out_size, -8888.f);
    return;
  }
  const int tcShift = __builtin_ctz(TC);
  const size_t rows = (size_t)NB * TC;

  char* ws = (char*)d_ws;
  size_t off = 0;
  auto alloc = [&](size_t bytes) -> void* {
    void* p = ws + off;
    off += (bytes + 255) & ~(size_t)255;
    return p;
  };
  unsigned* bar = (unsigned*)alloc(64 * sizeof(unsigned));
  float* hbuf   = (float*)alloc((size_t)2 * NB * HCAT * 4);
  float* cbuf   = (float*)alloc((size_t)NB * HCAT * 4);
  size_t staticEnd = off;
  bf16* hs      = (bf16*)alloc(rows * HCAT * 2);
  float* z      = (float*)alloc(rows * 256 * 4);
  bf16* gx0     = (bf16*)alloc(rows * 2048 * 2);
  bf16* gx1     = (bf16*)alloc(rows * 1024 * 2);
  bf16* gx2     = (bf16*)alloc(rows * 1024 * 2);

  // zero bar + hbuf + cbuf (h0 = c0 = 0); ws is poisoned 0xAA each call
  hipMemsetAsync(ws, 0, staticEnd, stream);

  dim3 blk(256);
  const int rb = (int)(rows / 64);   // row-blocks per chunk
  for (int t0 = 0; t0 < NT; t0 += TC) {
    k_gx<<<dim3(rb, 2048 / 64), blk, 0, stream>>>(x0, Wih0, bih0, bhh0, gx0, 300, 2048, t0, tcShift);
    k_gx<<<dim3(rb, 1024 / 64), blk, 0, stream>>>(x1, Wih1, bih1, bhh1, gx1, 74, 1024, t0, tcShift);
    k_gx<<<dim3(rb, 1024 / 64), blk, 0, stream>>>(x2, Wih2, bih2, bhh2, gx2, 35, 1024, t0, tcShift);

    k_lstm<<<dim3(512), blk, 0, stream>>>(Whh0, Whh1, Whh2, gx0, gx1, gx2,
                                          hbuf, cbuf, hs, bar, t0, TC);

    k_fc1<<<dim3(rb, 256 / 64), blk, 0, stream>>>(hs, W1, b1, z);
    k_fc2<<<dim3((int)(rows / 4)), blk, 0, stream>>>(z, W2, b2, out, t0, tcShift);
  }
}

// Round 3
// 6944.263 us; speedup vs baseline: 8.6832x; 8.6832x over previous
//
#include <hip/hip_runtime.h>
#include <hip/hip_bf16.h>
#include <math.h>

typedef __hip_bfloat16 bf16;
typedef unsigned short ushort_t;
typedef __attribute__((ext_vector_type(8))) short short8;
typedef __attribute__((ext_vector_type(4))) float f32x4;

constexpr int NB = 128;      // batch
constexpr int NT = 256;      // time
constexpr int HCAT = 1024;   // 512+256+256

__device__ inline float bf2f(ushort_t u) {
  union { unsigned i; float f; } x; x.i = (unsigned)u << 16; return x.f;
}
__device__ inline ushort_t f2bf(float f) {
  bf16 b = __float2bfloat16(f);
  return *reinterpret_cast<ushort_t*>(&b);
}

// ---------------------------------------------------------------------------
// gx = x @ W_ih^T + b_ih + b_hh   (fp32 compute, bf16 store), time-chunked.
// ---------------------------------------------------------------------------
__global__ __launch_bounds__(256) void k_gx(
    const float* __restrict__ x, const float* __restrict__ W,
    const float* __restrict__ bih, const float* __restrict__ bhh,
    bf16* __restrict__ gx, int d, int G, int t0, int tcShift)
{
  __shared__ float xs[32][68];
  __shared__ float ws_[32][68];
  const int bt0 = blockIdx.x * 64;
  const int r0  = blockIdx.y * 64;
  const int tid = threadIdx.x;
  const int tx = tid & 15;   // gate-row micro
  const int ty = tid >> 4;   // bt micro
  const int tcMask = (1 << tcShift) - 1;
  float acc[4][4];
#pragma unroll
  for (int p = 0; p < 4; ++p)
#pragma unroll
    for (int q = 0; q < 4; ++q) acc[p][q] = 0.f;

  for (int k0 = 0; k0 < d; k0 += 32) {
#pragma unroll
    for (int it = 0; it < 8; ++it) {
      int idx = tid + it * 256;
      int k = idx & 31, i = idx >> 5;
      int kk = k0 + k;
      int row = bt0 + i;
      int b = row >> tcShift, tl = row & tcMask;
      xs[k][i]  = (kk < d) ? x[((size_t)b * NT + t0 + tl) * d + kk] : 0.f;
      ws_[k][i] = (kk < d) ? W[(size_t)(r0 + i) * d + kk] : 0.f;
    }
    __syncthreads();
#pragma unroll 8
    for (int k = 0; k < 32; ++k) {
      float a[4], b[4];
#pragma unroll
      for (int p = 0; p < 4; ++p) a[p] = xs[k][ty * 4 + p];
#pragma unroll
      for (int q = 0; q < 4; ++q) b[q] = ws_[k][tx * 4 + q];
#pragma unroll
      for (int p = 0; p < 4; ++p)
#pragma unroll
        for (int q = 0; q < 4; ++q) acc[p][q] += a[p] * b[q];
    }
    __syncthreads();
  }
#pragma unroll
  for (int p = 0; p < 4; ++p) {
    int bt = bt0 + ty * 4 + p;
#pragma unroll
    for (int q = 0; q < 4; ++q) {
      int r = r0 + tx * 4 + q;
      float v = acc[p][q] + bih[r] + bhh[r];
      gx[(size_t)bt * G + r] = __float2bfloat16(v);
    }
  }
}

// ---------------------------------------------------------------------------
// fc1: Z = relu(A @ W1^T + b1)    A bf16 [rows,1024] (chunk), W fp32 [256,1024]
// ---------------------------------------------------------------------------
__global__ __launch_bounds__(256) void k_fc1(
    const bf16* __restrict__ A, const float* __restrict__ W,
    const float* __restrict__ bias, float* __restrict__ Z)
{
  __shared__ float xs[32][68];
  __shared__ float ws_[32][68];
  const int bt0 = blockIdx.x * 64;
  const int r0  = blockIdx.y * 64;
  const int tid = threadIdx.x;
  const int tx = tid & 15;
  const int ty = tid >> 4;
  float acc[4][4];
#pragma unroll
  for (int p = 0; p < 4; ++p)
#pragma unroll
    for (int q = 0; q < 4; ++q) acc[p][q] = 0.f;

  for (int k0 = 0; k0 < 1024; k0 += 32) {
#pragma unroll
    for (int it = 0; it < 8; ++it) {
      int idx = tid + it * 256;
      int k = idx & 31, i = idx >> 5;
      xs[k][i]  = __bfloat162float(A[(size_t)(bt0 + i) * 1024 + k0 + k]);
      ws_[k][i] = W[(size_t)(r0 + i) * 1024 + k0 + k];
    }
    __syncthreads();
#pragma unroll 8
    for (int k = 0; k < 32; ++k) {
      float a[4], b[4];
#pragma unroll
      for (int p = 0; p < 4; ++p) a[p] = xs[k][ty * 4 + p];
#pragma unroll
      for (int q = 0; q < 4; ++q) b[q] = ws_[k][tx * 4 + q];
#pragma unroll
      for (int p = 0; p < 4; ++p)
#pragma unroll
        for (int q = 0; q < 4; ++q) acc[p][q] += a[p] * b[q];
    }
    __syncthreads();
  }
#pragma unroll
  for (int p = 0; p < 4; ++p) {
    int bt = bt0 + ty * 4 + p;
#pragma unroll
    for (int q = 0; q < 4; ++q) {
      int r = r0 + tx * 4 + q;
      float v = acc[p][q] + bias[r];
      Z[(size_t)bt * 256 + r] = fmaxf(v, 0.f);
    }
  }
}

// ---------------------------------------------------------------------------
// fc2 + log_softmax: one wave per chunk row; map chunk row -> global (b,t)
// ---------------------------------------------------------------------------
__global__ __launch_bounds__(256) void k_fc2(
    const float* __restrict__ Z, const float* __restrict__ W2,
    const float* __restrict__ b2, float* __restrict__ out, int t0, int tcShift)
{
  const int wave = threadIdx.x >> 6;
  const int lane = threadIdx.x & 63;
  const int bt = blockIdx.x * 4 + wave;
  const float* z = Z + (size_t)bt * 256;
  float zv[4];
#pragma unroll
  for (int j = 0; j < 4; ++j) zv[j] = z[lane + 64 * j];
  float lg[7];
#pragma unroll
  for (int o = 0; o < 7; ++o) {
    float a = 0.f;
#pragma unroll
    for (int j = 0; j < 4; ++j) a += zv[j] * W2[o * 256 + lane + 64 * j];
#pragma unroll
    for (int off = 32; off > 0; off >>= 1) a += __shfl_down(a, off, 64);
    lg[o] = a;   // valid on lane 0
  }
  if (lane == 0) {
    const int b = bt >> tcShift;
    const int tl = bt & ((1 << tcShift) - 1);
    float* op = out + ((size_t)b * NT + t0 + tl) * 7;
    float lo[7];
    float m = -1e30f;
#pragma unroll
    for (int o = 0; o < 7; ++o) { lo[o] = lg[o] + b2[o]; m = fmaxf(m, lo[o]); }
    float s = 0.f;
#pragma unroll
    for (int o = 0; o < 7; ++o) s += expf(lo[o] - m);
    float lse = m + logf(s);
#pragma unroll
    for (int o = 0; o < 7; ++o) op[o] = lo[o] - lse;
  }
}

// ---------------------------------------------------------------------------
// Recurrent kernel: register-stationary bf16 weights + MFMA.
// 512 blocks (2/CU), 256 thr. group g = blockIdx%8 -> batch [16g,16g+16).
// rank = blockIdx/8: 0..31 -> LSTM0 (16 units each), 32..47 -> LSTM1, 48..63 -> LSTM2.
// Per (group,layer) spin barrier (32 or 16 blocks), monotone across chunks.
// Wave w computes gate w: D[16 batch][16 units] = h(16xHL) @ Wgate(16xHL)^T
// via HL/32 mfma_f32_16x16x32_bf16, B-frags held in VGPRs for all steps.
// ---------------------------------------------------------------------------
__device__ inline void group_barrier(unsigned* ctr, unsigned target) {
  __syncthreads();
  if (threadIdx.x == 0) {
    __hip_atomic_fetch_add(ctr, 1u, __ATOMIC_RELEASE, __HIP_MEMORY_SCOPE_AGENT);
    while (__hip_atomic_load(ctr, __ATOMIC_ACQUIRE, __HIP_MEMORY_SCOPE_AGENT) < target) {
      __builtin_amdgcn_s_sleep(2);
    }
  }
  __syncthreads();
}

template<int HL>
__device__ void lstm_body(const float* __restrict__ Whh,
                          const ushort_t* __restrict__ gx,   // bf16 bits, [NB][TC][4*HL]
                          ushort_t* __restrict__ hbuf,       // bf16 [2][NB][HCAT]
                          float* __restrict__ cbuf,          // fp32 [NB][HCAT]
                          ushort_t* __restrict__ hs,         // bf16 [NB][TC][HCAT]
                          float (*gbuf)[16][17],
                          unsigned* ctr, unsigned nblk,
                          int g, int u0, int hoff, int t0, int TC)
{
  constexpr int KC = HL / 32;
  const int tid  = threadIdx.x;
  const int lane = tid & 63;
  const int wgate = tid >> 6;        // wave index == gate (i,f,g,o)
  const int n    = lane & 15;        // B: unit within tile / A: batch within group
  const int quad = lane >> 4;

  // ---- load this wave's gate weights once into register B-fragments ----
  short8 wfrag[KC];
  {
    const float* wrow = Whh + ((size_t)wgate * HL + u0 + n) * HL + quad * 8;
#pragma unroll
    for (int kc = 0; kc < KC; ++kc) {
      short8 f;
#pragma unroll
      for (int j = 0; j < 8; ++j) f[j] = (short)f2bf(wrow[kc * 32 + j]);
      wfrag[kc] = f;
    }
  }

  // per-thread cell state mapping for the epilogue
  const int eu = tid & 15;           // unit
  const int eb = tid >> 4;           // batch within group
  const int bb = g * 16 + eb;
  const int hcol = hoff + u0 + eu;
  float c = cbuf[(size_t)bb * HCAT + hcol];

  const int abb = g * 16 + n;        // batch row this lane reads for A-frags

  for (int t = 0; t < TC; ++t) {
    const ushort_t* hrow =
        hbuf + ((size_t)(t & 1) * NB + abb) * HCAT + hoff + quad * 8;
    f32x4 acc = {0.f, 0.f, 0.f, 0.f};
#pragma unroll
    for (int kc = 0; kc < KC; ++kc) {
      short8 a = *reinterpret_cast<const short8*>(hrow + kc * 32);
      acc = __builtin_amdgcn_mfma_f32_16x16x32_bf16(a, wfrag[kc], acc, 0, 0, 0);
    }
    // D layout: col(unit)=lane&15, row(batch)=quad*4+r
#pragma unroll
    for (int r = 0; r < 4; ++r) gbuf[wgate][quad * 4 + r][n] = acc[r];
    __syncthreads();

    const size_t gxb = ((size_t)bb * TC + t) * (size_t)(4 * HL) + u0 + eu;
    float pi = gbuf[0][eb][eu] + bf2f(gx[gxb + 0 * (size_t)HL]);
    float pf = gbuf[1][eb][eu] + bf2f(gx[gxb + 1 * (size_t)HL]);
    float pg = gbuf[2][eb][eu] + bf2f(gx[gxb + 2 * (size_t)HL]);
    float po = gbuf[3][eb][eu] + bf2f(gx[gxb + 3 * (size_t)HL]);
    float si = 1.f / (1.f + expf(-pi));
    float sf = 1.f / (1.f + expf(-pf));
    float so = 1.f / (1.f + expf(-po));
    float tg = tanhf(pg);
    c = sf * c + si * tg;
    float h = so * tanhf(c);
    ushort_t hb = f2bf(h);
    hbuf[((size_t)((t + 1) & 1) * NB + bb) * HCAT + hcol] = hb;
    hs[((size_t)bb * TC + t) * HCAT + hcol] = hb;

    group_barrier(ctr, nblk * (unsigned)(t0 + t + 1));
  }
  cbuf[(size_t)bb * HCAT + hcol] = c;
}

__global__ __launch_bounds__(256, 2) void k_lstm(
    const float* __restrict__ Whh0, const float* __restrict__ Whh1,
    const float* __restrict__ Whh2,
    const ushort_t* __restrict__ gx0, const ushort_t* __restrict__ gx1,
    const ushort_t* __restrict__ gx2,
    ushort_t* __restrict__ hbuf, float* __restrict__ cbuf,
    ushort_t* __restrict__ hs,
    unsigned* __restrict__ bar,        // 24 counters, 128B apart
    int t0, int TC)
{
  __shared__ float gbuf[4][16][17];
  const int g    = blockIdx.x & 7;
  const int rank = blockIdx.x >> 3;
  if (rank < 32) {
    lstm_body<512>(Whh0, gx0, hbuf, cbuf, hs, gbuf, bar + (g * 3 + 0) * 32, 32u,
                   g, rank * 16, 0, t0, TC);
  } else if (rank < 48) {
    lstm_body<256>(Whh1, gx1, hbuf, cbuf, hs, gbuf, bar + (g * 3 + 1) * 32, 16u,
                   g, (rank - 32) * 16, 512, t0, TC);
  } else {
    lstm_body<256>(Whh2, gx2, hbuf, cbuf, hs, gbuf, bar + (g * 3 + 2) * 32, 16u,
                   g, (rank - 48) * 16, 768, t0, TC);
  }
}

// fallback if workspace is too small: distinctive sentinel
__global__ void k_fill(float* __restrict__ out, int n, float v) {
  int i = blockIdx.x * 256 + threadIdx.x;
  if (i < n) out[i] = v;
}

extern "C" void kernel_launch(void* const* d_in, const int* in_sizes, int n_in,
                              void* d_out, int out_size, void* d_ws, size_t ws_size,
                              hipStream_t stream) {
  (void)in_sizes; (void)n_in;
  const float* x0  = (const float*)d_in[0];
  const float* x1  = (const float*)d_in[1];
  const float* x2  = (const float*)d_in[2];
  const float* Wih0 = (const float*)d_in[3];
  const float* Whh0 = (const float*)d_in[4];
  const float* bih0 = (const float*)d_in[5];
  const float* bhh0 = (const float*)d_in[6];
  const float* Wih1 = (const float*)d_in[7];
  const float* Whh1 = (const float*)d_in[8];
  const float* bih1 = (const float*)d_in[9];
  const float* bhh1 = (const float*)d_in[10];
  const float* Wih2 = (const float*)d_in[11];
  const float* Whh2 = (const float*)d_in[12];
  const float* bih2 = (const float*)d_in[13];
  const float* bhh2 = (const float*)d_in[14];
  const float* W1 = (const float*)d_in[15];
  const float* b1 = (const float*)d_in[16];
  const float* W2 = (const float*)d_in[17];
  const float* b2 = (const float*)d_in[18];
  float* out = (float*)d_out;

  // pick largest even chunk TC that fits in ws
  const int cands[6] = {256, 128, 64, 32, 16, 8};
  int TC = 0;
  for (int ci = 0; ci < 6; ++ci) {
    int tc = cands[ci];
    size_t rows = (size_t)NB * tc;
    size_t o = 0;
    auto al = [&](size_t bytes) { o += (bytes + 255) & ~(size_t)255; };
    al(24 * 32 * sizeof(unsigned));     // bar
    al((size_t)2 * NB * HCAT * 2);      // hbuf (bf16)
    al((size_t)NB * HCAT * 4);          // cbuf (fp32)
    al(rows * HCAT * 2);                // hs chunk
    al(rows * 256 * 4);                 // z chunk
    al(rows * 2048 * 2);                // gx0 chunk
    al(rows * 1024 * 2);                // gx1 chunk
    al(rows * 1024 * 2);                // gx2 chunk
    if (o <= ws_size) { TC = tc; break; }
  }
  if (TC == 0) {
    k_fill<<<dim3((out_size + 255) / 256), dim3(256), 0, stream>>>(out, out_size, -8888.f);
    return;
  }
  const int tcShift = __builtin_ctz(TC);
  const size_t rows = (size_t)NB * TC;

  char* ws = (char*)d_ws;
  size_t off = 0;
  auto alloc = [&](size_t bytes) -> void* {
    void* p = ws + off;
    off += (bytes + 255) & ~(size_t)255;
    return p;
  };
  unsigned* bar  = (unsigned*)alloc(24 * 32 * sizeof(unsigned));
  ushort_t* hbuf = (ushort_t*)alloc((size_t)2 * NB * HCAT * 2);
  float* cbuf    = (float*)alloc((size_t)NB * HCAT * 4);
  size_t staticEnd = off;
  ushort_t* hs   = (ushort_t*)alloc(rows * HCAT * 2);
  float* z       = (float*)alloc(rows * 256 * 4);
  bf16* gx0      = (bf16*)alloc(rows * 2048 * 2);
  bf16* gx1      = (bf16*)alloc(rows * 1024 * 2);
  bf16* gx2      = (bf16*)alloc(rows * 1024 * 2);

  // zero bar + hbuf + cbuf (h0 = c0 = 0)
  hipMemsetAsync(ws, 0, staticEnd, stream);

  dim3 blk(256);
  const int rb = (int)(rows / 64);   // row-blocks per chunk
  for (int t0 = 0; t0 < NT; t0 += TC) {
    k_gx<<<dim3(rb, 2048 / 64), blk, 0, stream>>>(x0, Wih0, bih0, bhh0, gx0, 300, 2048, t0, tcShift);
    k_gx<<<dim3(rb, 1024 / 64), blk, 0, stream>>>(x1, Wih1, bih1, bhh1, gx1, 74, 1024, t0, tcShift);
    k_gx<<<dim3(rb, 1024 / 64), blk, 0, stream>>>(x2, Wih2, bih2, bhh2, gx2, 35, 1024, t0, tcShift);

    k_lstm<<<dim3(512), blk, 0, stream>>>(Whh0, Whh1, Whh2,
                                          (const ushort_t*)gx0, (const ushort_t*)gx1,
                                          (const ushort_t*)gx2,
                                          hbuf, cbuf, hs, bar, t0, TC);

    k_fc1<<<dim3(rb, 256 / 64), blk, 0, stream>>>((const bf16*)hs, W1, b1, z);
    k_fc2<<<dim3((int)(rows / 4)), blk, 0, stream>>>(z, W2, b2, out, t0, tcShift);
  }
}

// Round 4
// 5359.657 us; speedup vs baseline: 11.2504x; 1.2957x over previous
//
#include <hip/hip_runtime.h>
#include <hip/hip_bf16.h>
#include <math.h>

typedef __hip_bfloat16 bf16;
typedef unsigned short ushort_t;
typedef __attribute__((ext_vector_type(8))) short short8;
typedef __attribute__((ext_vector_type(4))) float f32x4;

constexpr int NB = 128;      // batch
constexpr int NT = 256;      // time
constexpr int HCAT = 1024;   // 512+256+256

__device__ inline float bf2f(ushort_t u) {
  union { unsigned i; float f; } x; x.i = (unsigned)u << 16; return x.f;
}
__device__ inline ushort_t f2bf(float f) {
  bf16 b = __float2bfloat16(f);
  return *reinterpret_cast<ushort_t*>(&b);
}

// ---------------------------------------------------------------------------
// gx = x @ W_ih^T + b_ih + b_hh   (fp32 compute, bf16 store), time-chunked.
// ---------------------------------------------------------------------------
__global__ __launch_bounds__(256) void k_gx(
    const float* __restrict__ x, const float* __restrict__ W,
    const float* __restrict__ bih, const float* __restrict__ bhh,
    bf16* __restrict__ gx, int d, int G, int t0, int tcShift)
{
  __shared__ float xs[32][68];
  __shared__ float ws_[32][68];
  const int bt0 = blockIdx.x * 64;
  const int r0  = blockIdx.y * 64;
  const int tid = threadIdx.x;
  const int tx = tid & 15;   // gate-row micro
  const int ty = tid >> 4;   // bt micro
  const int tcMask = (1 << tcShift) - 1;
  float acc[4][4];
#pragma unroll
  for (int p = 0; p < 4; ++p)
#pragma unroll
    for (int q = 0; q < 4; ++q) acc[p][q] = 0.f;

  for (int k0 = 0; k0 < d; k0 += 32) {
#pragma unroll
    for (int it = 0; it < 8; ++it) {
      int idx = tid + it * 256;
      int k = idx & 31, i = idx >> 5;
      int kk = k0 + k;
      int row = bt0 + i;
      int b = row >> tcShift, tl = row & tcMask;
      xs[k][i]  = (kk < d) ? x[((size_t)b * NT + t0 + tl) * d + kk] : 0.f;
      ws_[k][i] = (kk < d) ? W[(size_t)(r0 + i) * d + kk] : 0.f;
    }
    __syncthreads();
#pragma unroll 8
    for (int k = 0; k < 32; ++k) {
      float a[4], b[4];
#pragma unroll
      for (int p = 0; p < 4; ++p) a[p] = xs[k][ty * 4 + p];
#pragma unroll
      for (int q = 0; q < 4; ++q) b[q] = ws_[k][tx * 4 + q];
#pragma unroll
      for (int p = 0; p < 4; ++p)
#pragma unroll
        for (int q = 0; q < 4; ++q) acc[p][q] += a[p] * b[q];
    }
    __syncthreads();
  }
#pragma unroll
  for (int p = 0; p < 4; ++p) {
    int bt = bt0 + ty * 4 + p;
#pragma unroll
    for (int q = 0; q < 4; ++q) {
      int r = r0 + tx * 4 + q;
      float v = acc[p][q] + bih[r] + bhh[r];
      gx[(size_t)bt * G + r] = __float2bfloat16(v);
    }
  }
}

// ---------------------------------------------------------------------------
// fc1: Z = relu(A @ W1^T + b1)    A bf16 [rows,1024] (chunk), W fp32 [256,1024]
// ---------------------------------------------------------------------------
__global__ __launch_bounds__(256) void k_fc1(
    const bf16* __restrict__ A, const float* __restrict__ W,
    const float* __restrict__ bias, float* __restrict__ Z)
{
  __shared__ float xs[32][68];
  __shared__ float ws_[32][68];
  const int bt0 = blockIdx.x * 64;
  const int r0  = blockIdx.y * 64;
  const int tid = threadIdx.x;
  const int tx = tid & 15;
  const int ty = tid >> 4;
  float acc[4][4];
#pragma unroll
  for (int p = 0; p < 4; ++p)
#pragma unroll
    for (int q = 0; q < 4; ++q) acc[p][q] = 0.f;

  for (int k0 = 0; k0 < 1024; k0 += 32) {
#pragma unroll
    for (int it = 0; it < 8; ++it) {
      int idx = tid + it * 256;
      int k = idx & 31, i = idx >> 5;
      xs[k][i]  = __bfloat162float(A[(size_t)(bt0 + i) * 1024 + k0 + k]);
      ws_[k][i] = W[(size_t)(r0 + i) * 1024 + k0 + k];
    }
    __syncthreads();
#pragma unroll 8
    for (int k = 0; k < 32; ++k) {
      float a[4], b[4];
#pragma unroll
      for (int p = 0; p < 4; ++p) a[p] = xs[k][ty * 4 + p];
#pragma unroll
      for (int q = 0; q < 4; ++q) b[q] = ws_[k][tx * 4 + q];
#pragma unroll
      for (int p = 0; p < 4; ++p)
#pragma unroll
        for (int q = 0; q < 4; ++q) acc[p][q] += a[p] * b[q];
    }
    __syncthreads();
  }
#pragma unroll
  for (int p = 0; p < 4; ++p) {
    int bt = bt0 + ty * 4 + p;
#pragma unroll
    for (int q = 0; q < 4; ++q) {
      int r = r0 + tx * 4 + q;
      float v = acc[p][q] + bias[r];
      Z[(size_t)bt * 256 + r] = fmaxf(v, 0.f);
    }
  }
}

// ---------------------------------------------------------------------------
// fc2 + log_softmax: one wave per chunk row; map chunk row -> global (b,t)
// ---------------------------------------------------------------------------
__global__ __launch_bounds__(256) void k_fc2(
    const float* __restrict__ Z, const float* __restrict__ W2,
    const float* __restrict__ b2, float* __restrict__ out, int t0, int tcShift)
{
  const int wave = threadIdx.x >> 6;
  const int lane = threadIdx.x & 63;
  const int bt = blockIdx.x * 4 + wave;
  const float* z = Z + (size_t)bt * 256;
  float zv[4];
#pragma unroll
  for (int j = 0; j < 4; ++j) zv[j] = z[lane + 64 * j];
  float lg[7];
#pragma unroll
  for (int o = 0; o < 7; ++o) {
    float a = 0.f;
#pragma unroll
    for (int j = 0; j < 4; ++j) a += zv[j] * W2[o * 256 + lane + 64 * j];
#pragma unroll
    for (int off = 32; off > 0; off >>= 1) a += __shfl_down(a, off, 64);
    lg[o] = a;   // valid on lane 0
  }
  if (lane == 0) {
    const int b = bt >> tcShift;
    const int tl = bt & ((1 << tcShift) - 1);
    float* op = out + ((size_t)b * NT + t0 + tl) * 7;
    float lo[7];
    float m = -1e30f;
#pragma unroll
    for (int o = 0; o < 7; ++o) { lo[o] = lg[o] + b2[o]; m = fmaxf(m, lo[o]); }
    float s = 0.f;
#pragma unroll
    for (int o = 0; o < 7; ++o) s += expf(lo[o] - m);
    float lse = m + logf(s);
#pragma unroll
    for (int o = 0; o < 7; ++o) op[o] = lo[o] - lse;
  }
}

// ---------------------------------------------------------------------------
// Recurrent kernel: register-stationary bf16 weights + MFMA.
// Barrier: RELAXED spin (no per-poll cache invalidation!) + single ACQUIRE
// load after the target is reached. The old per-iteration ACQUIRE emitted
// buffer_inv each poll -> chip-wide continuous L1/L2 invalidation (22 us/step).
// ---------------------------------------------------------------------------
__device__ inline void group_barrier(unsigned* ctr, unsigned target) {
  __syncthreads();
  if (threadIdx.x == 0) {
    __hip_atomic_fetch_add(ctr, 1u, __ATOMIC_RELEASE, __HIP_MEMORY_SCOPE_AGENT);
    while (__hip_atomic_load(ctr, __ATOMIC_RELAXED, __HIP_MEMORY_SCOPE_AGENT) < target) {
      __builtin_amdgcn_s_sleep(1);
    }
    (void)__hip_atomic_load(ctr, __ATOMIC_ACQUIRE, __HIP_MEMORY_SCOPE_AGENT);
  }
  __syncthreads();
}

template<int HL>
__device__ void lstm_body(const float* __restrict__ Whh,
                          const ushort_t* __restrict__ gx,   // bf16 bits, [NB][TC][4*HL]
                          ushort_t* __restrict__ hbuf,       // bf16 [2][NB][HCAT]
                          float* __restrict__ cbuf,          // fp32 [NB][HCAT]
                          ushort_t* __restrict__ hs,         // bf16 [NB][TC][HCAT]
                          float (*gbuf)[16][17],
                          unsigned* ctr, unsigned nblk,
                          int g, int u0, int hoff, int t0, int TC)
{
  constexpr int KC = HL / 32;
  const int tid  = threadIdx.x;
  const int lane = tid & 63;
  const int wgate = tid >> 6;        // wave index == gate (i,f,g,o)
  const int n    = lane & 15;        // B: unit within tile / A: batch within group
  const int quad = lane >> 4;

  // ---- load this wave's gate weights once into register B-fragments ----
  short8 wfrag[KC];
  {
    const float* wrow = Whh + ((size_t)wgate * HL + u0 + n) * HL + quad * 8;
#pragma unroll
    for (int kc = 0; kc < KC; ++kc) {
      short8 f;
#pragma unroll
      for (int j = 0; j < 8; ++j) f[j] = (short)f2bf(wrow[kc * 32 + j]);
      wfrag[kc] = f;
    }
  }

  // per-thread cell state mapping for the epilogue
  const int eu = tid & 15;           // unit
  const int eb = tid >> 4;           // batch within group
  const int bb = g * 16 + eb;
  const int hcol = hoff + u0 + eu;
  float c = cbuf[(size_t)bb * HCAT + hcol];

  const int abb = g * 16 + n;        // batch row this lane reads for A-frags

  // gx prefetch: values for step t live in registers across the t-1 barrier
  const ushort_t* gxp = gx + (size_t)bb * TC * (size_t)(4 * HL) + u0 + eu;
  float gxv[4];
#pragma unroll
  for (int q = 0; q < 4; ++q) gxv[q] = bf2f(gxp[(size_t)q * HL]);

  for (int t = 0; t < TC; ++t) {
    const ushort_t* hrow =
        hbuf + ((size_t)(t & 1) * NB + abb) * HCAT + hoff + quad * 8;
    f32x4 acc = {0.f, 0.f, 0.f, 0.f};
#pragma unroll
    for (int kc = 0; kc < KC; ++kc) {
      short8 a = *reinterpret_cast<const short8*>(hrow + kc * 32);
      acc = __builtin_amdgcn_mfma_f32_16x16x32_bf16(a, wfrag[kc], acc, 0, 0, 0);
    }
    // D layout: col(unit)=lane&15, row(batch)=quad*4+r
#pragma unroll
    for (int r = 0; r < 4; ++r) gbuf[wgate][quad * 4 + r][n] = acc[r];
    __syncthreads();

    float pi = gbuf[0][eb][eu] + gxv[0];
    float pf = gbuf[1][eb][eu] + gxv[1];
    float pg = gbuf[2][eb][eu] + gxv[2];
    float po = gbuf[3][eb][eu] + gxv[3];
    float si = 1.f / (1.f + expf(-pi));
    float sf = 1.f / (1.f + expf(-pf));
    float so = 1.f / (1.f + expf(-po));
    float tg = tanhf(pg);
    c = sf * c + si * tg;
    float h = so * tanhf(c);
    ushort_t hb = f2bf(h);
    hbuf[((size_t)((t + 1) & 1) * NB + bb) * HCAT + hcol] = hb;
    hs[((size_t)bb * TC + t) * HCAT + hcol] = hb;

    // prefetch gx for t+1 BEFORE the barrier: loads complete during the spin
    if (t + 1 < TC) {
#pragma unroll
      for (int q = 0; q < 4; ++q)
        gxv[q] = bf2f(gxp[((size_t)(t + 1) * 4 + q) * (size_t)HL]);
    }

    group_barrier(ctr, nblk * (unsigned)(t0 + t + 1));
  }
  cbuf[(size_t)bb * HCAT + hcol] = c;
}

__global__ __launch_bounds__(256, 2) void k_lstm(
    const float* __restrict__ Whh0, const float* __restrict__ Whh1,
    const float* __restrict__ Whh2,
    const ushort_t* __restrict__ gx0, const ushort_t* __restrict__ gx1,
    const ushort_t* __restrict__ gx2,
    ushort_t* __restrict__ hbuf, float* __restrict__ cbuf,
    ushort_t* __restrict__ hs,
    unsigned* __restrict__ bar,        // 24 counters, 128B apart
    int t0, int TC)
{
  __shared__ float gbuf[4][16][17];
  const int g    = blockIdx.x & 7;
  const int rank = blockIdx.x >> 3;
  if (rank < 32) {
    lstm_body<512>(Whh0, gx0, hbuf, cbuf, hs, gbuf, bar + (g * 3 + 0) * 32, 32u,
                   g, rank * 16, 0, t0, TC);
  } else if (rank < 48) {
    lstm_body<256>(Whh1, gx1, hbuf, cbuf, hs, gbuf, bar + (g * 3 + 1) * 32, 16u,
                   g, (rank - 32) * 16, 512, t0, TC);
  } else {
    lstm_body<256>(Whh2, gx2, hbuf, cbuf, hs, gbuf, bar + (g * 3 + 2) * 32, 16u,
                   g, (rank - 48) * 16, 768, t0, TC);
  }
}

// fallback if workspace is too small: distinctive sentinel
__global__ void k_fill(float* __restrict__ out, int n, float v) {
  int i = blockIdx.x * 256 + threadIdx.x;
  if (i < n) out[i] = v;
}

extern "C" void kernel_launch(void* const* d_in, const int* in_sizes, int n_in,
                              void* d_out, int out_size, void* d_ws, size_t ws_size,
                              hipStream_t stream) {
  (void)in_sizes; (void)n_in;
  const float* x0  = (const float*)d_in[0];
  const float* x1  = (const float*)d_in[1];
  const float* x2  = (const float*)d_in[2];
  const float* Wih0 = (const float*)d_in[3];
  const float* Whh0 = (const float*)d_in[4];
  const float* bih0 = (const float*)d_in[5];
  const float* bhh0 = (const float*)d_in[6];
  const float* Wih1 = (const float*)d_in[7];
  const float* Whh1 = (const float*)d_in[8];
  const float* bih1 = (const float*)d_in[9];
  const float* bhh1 = (const float*)d_in[10];
  const float* Wih2 = (const float*)d_in[11];
  const float* Whh2 = (const float*)d_in[12];
  const float* bih2 = (const float*)d_in[13];
  const float* bhh2 = (const float*)d_in[14];
  const float* W1 = (const float*)d_in[15];
  const float* b1 = (const float*)d_in[16];
  const float* W2 = (const float*)d_in[17];
  const float* b2 = (const float*)d_in[18];
  float* out = (float*)d_out;

  // pick largest even chunk TC that fits in ws
  const int cands[6] = {256, 128, 64, 32, 16, 8};
  int TC = 0;
  for (int ci = 0; ci < 6; ++ci) {
    int tc = cands[ci];
    size_t rows = (size_t)NB * tc;
    size_t o = 0;
    auto al = [&](size_t bytes) { o += (bytes + 255) & ~(size_t)255; };
    al(24 * 32 * sizeof(unsigned));     // bar
    al((size_t)2 * NB * HCAT * 2);      // hbuf (bf16)
    al((size_t)NB * HCAT * 4);          // cbuf (fp32)
    al(rows * HCAT * 2);                // hs chunk
    al(rows * 256 * 4);                 // z chunk
    al(rows * 2048 * 2);                // gx0 chunk
    al(rows * 1024 * 2);                // gx1 chunk
    al(rows * 1024 * 2);                // gx2 chunk
    if (o <= ws_size) { TC = tc; break; }
  }
  if (TC == 0) {
    k_fill<<<dim3((out_size + 255) / 256), dim3(256), 0, stream>>>(out, out_size, -8888.f);
    return;
  }
  const int tcShift = __builtin_ctz(TC);
  const size_t rows = (size_t)NB * TC;

  char* ws = (char*)d_ws;
  size_t off = 0;
  auto alloc = [&](size_t bytes) -> void* {
    void* p = ws + off;
    off += (bytes + 255) & ~(size_t)255;
    return p;
  };
  unsigned* bar  = (unsigned*)alloc(24 * 32 * sizeof(unsigned));
  ushort_t* hbuf = (ushort_t*)alloc((size_t)2 * NB * HCAT * 2);
  float* cbuf    = (float*)alloc((size_t)NB * HCAT * 4);
  size_t staticEnd = off;
  ushort_t* hs   = (ushort_t*)alloc(rows * HCAT * 2);
  float* z       = (float*)alloc(rows * 256 * 4);
  bf16* gx0      = (bf16*)alloc(rows * 2048 * 2);
  bf16* gx1      = (bf16*)alloc(rows * 1024 * 2);
  bf16* gx2      = (bf16*)alloc(rows * 1024 * 2);

  // zero bar + hbuf + cbuf (h0 = c0 = 0)
  hipMemsetAsync(ws, 0, staticEnd, stream);

  dim3 blk(256);
  const int rb = (int)(rows / 64);   // row-blocks per chunk
  for (int t0 = 0; t0 < NT; t0 += TC) {
    k_gx<<<dim3(rb, 2048 / 64), blk, 0, stream>>>(x0, Wih0, bih0, bhh0, gx0, 300, 2048, t0, tcShift);
    k_gx<<<dim3(rb, 1024 / 64), blk, 0, stream>>>(x1, Wih1, bih1, bhh1, gx1, 74, 1024, t0, tcShift);
    k_gx<<<dim3(rb, 1024 / 64), blk, 0, stream>>>(x2, Wih2, bih2, bhh2, gx2, 35, 1024, t0, tcShift);

    k_lstm<<<dim3(512), blk, 0, stream>>>(Whh0, Whh1, Whh2,
                                          (const ushort_t*)gx0, (const ushort_t*)gx1,
                                          (const ushort_t*)gx2,
                                          hbuf, cbuf, hs, bar, t0, TC);

    k_fc1<<<dim3(rb, 256 / 64), blk, 0, stream>>>((const bf16*)hs, W1, b1, z);
    k_fc2<<<dim3((int)(rows / 4)), blk, 0, stream>>>(z, W2, b2, out, t0, tcShift);
  }
}

// Round 5
// 3467.747 us; speedup vs baseline: 17.3884x; 1.5456x over previous
//
#include <hip/hip_runtime.h>
#include <hip/hip_bf16.h>
#include <math.h>

typedef __hip_bfloat16 bf16;
typedef unsigned short ushort_t;
typedef __attribute__((ext_vector_type(8))) short short8;
typedef __attribute__((ext_vector_type(4))) float f32x4;

constexpr int NB = 128;      // batch
constexpr int NT = 256;      // time
constexpr int HCAT = 1024;   // 512+256+256

__device__ inline float bf2f(ushort_t u) {
  union { unsigned i; float f; } x; x.i = (unsigned)u << 16; return x.f;
}
__device__ inline ushort_t f2bf(float f) {
  bf16 b = __float2bfloat16(f);
  return *reinterpret_cast<ushort_t*>(&b);
}

// LLC-coherent (agent-scope, relaxed => no cache-maintenance) 16B h-frag load
__device__ inline short8 ldh16(const ushort_t* p) {
  union { unsigned long long u[2]; short8 v; } x;
  unsigned long long* q = const_cast<unsigned long long*>(
      reinterpret_cast<const unsigned long long*>(p));
  x.u[0] = __hip_atomic_load(q,     __ATOMIC_RELAXED, __HIP_MEMORY_SCOPE_AGENT);
  x.u[1] = __hip_atomic_load(q + 1, __ATOMIC_RELAXED, __HIP_MEMORY_SCOPE_AGENT);
  return x.v;
}

// ---------------------------------------------------------------------------
// gx = x @ W_ih^T + b_ih + b_hh   (fp32 compute, bf16 store), time-chunked.
// ---------------------------------------------------------------------------
__global__ __launch_bounds__(256) void k_gx(
    const float* __restrict__ x, const float* __restrict__ W,
    const float* __restrict__ bih, const float* __restrict__ bhh,
    bf16* __restrict__ gx, int d, int G, int t0, int tcShift)
{
  __shared__ float xs[32][68];
  __shared__ float ws_[32][68];
  const int bt0 = blockIdx.x * 64;
  const int r0  = blockIdx.y * 64;
  const int tid = threadIdx.x;
  const int tx = tid & 15;   // gate-row micro
  const int ty = tid >> 4;   // bt micro
  const int tcMask = (1 << tcShift) - 1;
  float acc[4][4];
#pragma unroll
  for (int p = 0; p < 4; ++p)
#pragma unroll
    for (int q = 0; q < 4; ++q) acc[p][q] = 0.f;

  for (int k0 = 0; k0 < d; k0 += 32) {
#pragma unroll
    for (int it = 0; it < 8; ++it) {
      int idx = tid + it * 256;
      int k = idx & 31, i = idx >> 5;
      int kk = k0 + k;
      int row = bt0 + i;
      int b = row >> tcShift, tl = row & tcMask;
      xs[k][i]  = (kk < d) ? x[((size_t)b * NT + t0 + tl) * d + kk] : 0.f;
      ws_[k][i] = (kk < d) ? W[(size_t)(r0 + i) * d + kk] : 0.f;
    }
    __syncthreads();
#pragma unroll 8
    for (int k = 0; k < 32; ++k) {
      float a[4], b[4];
#pragma unroll
      for (int p = 0; p < 4; ++p) a[p] = xs[k][ty * 4 + p];
#pragma unroll
      for (int q = 0; q < 4; ++q) b[q] = ws_[k][tx * 4 + q];
#pragma unroll
      for (int p = 0; p < 4; ++p)
#pragma unroll
        for (int q = 0; q < 4; ++q) acc[p][q] += a[p] * b[q];
    }
    __syncthreads();
  }
#pragma unroll
  for (int p = 0; p < 4; ++p) {
    int bt = bt0 + ty * 4 + p;
#pragma unroll
    for (int q = 0; q < 4; ++q) {
      int r = r0 + tx * 4 + q;
      float v = acc[p][q] + bih[r] + bhh[r];
      gx[(size_t)bt * G + r] = __float2bfloat16(v);
    }
  }
}

// ---------------------------------------------------------------------------
// fc1: Z = relu(A @ W1^T + b1)    A bf16 [rows,1024] (chunk), W fp32 [256,1024]
// ---------------------------------------------------------------------------
__global__ __launch_bounds__(256) void k_fc1(
    const bf16* __restrict__ A, const float* __restrict__ W,
    const float* __restrict__ bias, float* __restrict__ Z)
{
  __shared__ float xs[32][68];
  __shared__ float ws_[32][68];
  const int bt0 = blockIdx.x * 64;
  const int r0  = blockIdx.y * 64;
  const int tid = threadIdx.x;
  const int tx = tid & 15;
  const int ty = tid >> 4;
  float acc[4][4];
#pragma unroll
  for (int p = 0; p < 4; ++p)
#pragma unroll
    for (int q = 0; q < 4; ++q) acc[p][q] = 0.f;

  for (int k0 = 0; k0 < 1024; k0 += 32) {
#pragma unroll
    for (int it = 0; it < 8; ++it) {
      int idx = tid + it * 256;
      int k = idx & 31, i = idx >> 5;
      xs[k][i]  = __bfloat162float(A[(size_t)(bt0 + i) * 1024 + k0 + k]);
      ws_[k][i] = W[(size_t)(r0 + i) * 1024 + k0 + k];
    }
    __syncthreads();
#pragma unroll 8
    for (int k = 0; k < 32; ++k) {
      float a[4], b[4];
#pragma unroll
      for (int p = 0; p < 4; ++p) a[p] = xs[k][ty * 4 + p];
#pragma unroll
      for (int q = 0; q < 4; ++q) b[q] = ws_[k][tx * 4 + q];
#pragma unroll
      for (int p = 0; p < 4; ++p)
#pragma unroll
        for (int q = 0; q < 4; ++q) acc[p][q] += a[p] * b[q];
    }
    __syncthreads();
  }
#pragma unroll
  for (int p = 0; p < 4; ++p) {
    int bt = bt0 + ty * 4 + p;
#pragma unroll
    for (int q = 0; q < 4; ++q) {
      int r = r0 + tx * 4 + q;
      float v = acc[p][q] + bias[r];
      Z[(size_t)bt * 256 + r] = fmaxf(v, 0.f);
    }
  }
}

// ---------------------------------------------------------------------------
// fc2 + log_softmax: one wave per chunk row; map chunk row -> global (b,t)
// ---------------------------------------------------------------------------
__global__ __launch_bounds__(256) void k_fc2(
    const float* __restrict__ Z, const float* __restrict__ W2,
    const float* __restrict__ b2, float* __restrict__ out, int t0, int tcShift)
{
  const int wave = threadIdx.x >> 6;
  const int lane = threadIdx.x & 63;
  const int bt = blockIdx.x * 4 + wave;
  const float* z = Z + (size_t)bt * 256;
  float zv[4];
#pragma unroll
  for (int j = 0; j < 4; ++j) zv[j] = z[lane + 64 * j];
  float lg[7];
#pragma unroll
  for (int o = 0; o < 7; ++o) {
    float a = 0.f;
#pragma unroll
    for (int j = 0; j < 4; ++j) a += zv[j] * W2[o * 256 + lane + 64 * j];
#pragma unroll
    for (int off = 32; off > 0; off >>= 1) a += __shfl_down(a, off, 64);
    lg[o] = a;   // valid on lane 0
  }
  if (lane == 0) {
    const int b = bt >> tcShift;
    const int tl = bt & ((1 << tcShift) - 1);
    float* op = out + ((size_t)b * NT + t0 + tl) * 7;
    float lo[7];
    float m = -1e30f;
#pragma unroll
    for (int o = 0; o < 7; ++o) { lo[o] = lg[o] + b2[o]; m = fmaxf(m, lo[o]); }
    float s = 0.f;
#pragma unroll
    for (int o = 0; o < 7; ++o) s += expf(lo[o] - m);
    float lse = m + logf(s);
#pragma unroll
    for (int o = 0; o < 7; ++o) op[o] = lo[o] - lse;
  }
}

// ---------------------------------------------------------------------------
// Recurrent kernel: register-stationary bf16 weights + MFMA.
// Synchronization: ALL-RELAXED agent atomics. No acquire/release fences =>
// no buffer_wbl2 / buffer_inv per step (R4's residual 16us/step). Exchanged
// data (hbuf) moves via relaxed agent atomic stores/loads (sc-routed, LLC-
// coherent). Ordering: __syncthreads() drains vmcnt before the counter add;
// readers issue h loads only after the post-spin __syncthreads().
// gx/weights now stay cached in L1/L2 across all steps.
// ---------------------------------------------------------------------------
__device__ inline void group_barrier(unsigned* ctr, unsigned target) {
  __syncthreads();   // drains vmcnt(0): all h stores of this block completed
  if (threadIdx.x == 0) {
    __hip_atomic_fetch_add(ctr, 1u, __ATOMIC_RELAXED, __HIP_MEMORY_SCOPE_AGENT);
    while (__hip_atomic_load(ctr, __ATOMIC_RELAXED, __HIP_MEMORY_SCOPE_AGENT) < target) {
      __builtin_amdgcn_s_sleep(1);
    }
  }
  __syncthreads();
}

template<int HL>
__device__ void lstm_body(const float* __restrict__ Whh,
                          const ushort_t* __restrict__ gx,   // bf16 bits, [NB][TC][4*HL]
                          ushort_t* __restrict__ hbuf,       // bf16 [2][NB][HCAT]
                          float* __restrict__ cbuf,          // fp32 [NB][HCAT]
                          ushort_t* __restrict__ hs,         // bf16 [NB][TC][HCAT]
                          float (*gbuf)[16][17],
                          unsigned* ctr, unsigned nblk,
                          int g, int u0, int hoff, int t0, int TC)
{
  constexpr int KC = HL / 32;
  const int tid  = threadIdx.x;
  const int lane = tid & 63;
  const int wgate = tid >> 6;        // wave index == gate (i,f,g,o)
  const int n    = lane & 15;        // B: unit within tile / A: batch within group
  const int quad = lane >> 4;

  // ---- load this wave's gate weights once into register B-fragments ----
  short8 wfrag[KC];
  {
    const float* wrow = Whh + ((size_t)wgate * HL + u0 + n) * HL + quad * 8;
#pragma unroll
    for (int kc = 0; kc < KC; ++kc) {
      short8 f;
#pragma unroll
      for (int j = 0; j < 8; ++j) f[j] = (short)f2bf(wrow[kc * 32 + j]);
      wfrag[kc] = f;
    }
  }

  // per-thread cell state mapping for the epilogue
  const int eu = tid & 15;           // unit
  const int eb = tid >> 4;           // batch within group
  const int bb = g * 16 + eb;
  const int hcol = hoff + u0 + eu;
  float c = cbuf[(size_t)bb * HCAT + hcol];

  const int abb = g * 16 + n;        // batch row this lane reads for A-frags

  // gx prefetch: values for step t live in registers across the t-1 barrier
  const ushort_t* gxp = gx + (size_t)bb * TC * (size_t)(4 * HL) + u0 + eu;
  float gxv[4];
#pragma unroll
  for (int q = 0; q < 4; ++q) gxv[q] = bf2f(gxp[(size_t)q * HL]);

  for (int t = 0; t < TC; ++t) {
    const ushort_t* hrow =
        hbuf + ((size_t)(t & 1) * NB + abb) * HCAT + hoff + quad * 8;
    f32x4 acc = {0.f, 0.f, 0.f, 0.f};
#pragma unroll
    for (int kc = 0; kc < KC; ++kc) {
      short8 a = ldh16(hrow + kc * 32);
      acc = __builtin_amdgcn_mfma_f32_16x16x32_bf16(a, wfrag[kc], acc, 0, 0, 0);
    }
    // D layout: col(unit)=lane&15, row(batch)=quad*4+r
#pragma unroll
    for (int r = 0; r < 4; ++r) gbuf[wgate][quad * 4 + r][n] = acc[r];
    __syncthreads();

    float pi = gbuf[0][eb][eu] + gxv[0];
    float pf = gbuf[1][eb][eu] + gxv[1];
    float pg = gbuf[2][eb][eu] + gxv[2];
    float po = gbuf[3][eb][eu] + gxv[3];
    float si = 1.f / (1.f + expf(-pi));
    float sf = 1.f / (1.f + expf(-pf));
    float so = 1.f / (1.f + expf(-po));
    float tg = tanhf(pg);
    c = sf * c + si * tg;
    float h = so * tanhf(c);
    ushort_t hb = f2bf(h);

    // pair adjacent units' bf16 into one 4B relaxed agent atomic store (LLC)
    unsigned nbv = (unsigned)(ushort_t)__shfl_down((int)hb, 1, 64);
    if ((eu & 1) == 0) {
      unsigned paired = (unsigned)hb | (nbv << 16);
      unsigned* dst = reinterpret_cast<unsigned*>(
          hbuf + ((size_t)((t + 1) & 1) * NB + bb) * HCAT) + (hcol >> 1);
      __hip_atomic_store(dst, paired, __ATOMIC_RELAXED, __HIP_MEMORY_SCOPE_AGENT);
    }
    hs[((size_t)bb * TC + t) * HCAT + hcol] = hb;   // normal store (next kernel)

    // prefetch gx for t+1 BEFORE the barrier: loads complete during the spin
    if (t + 1 < TC) {
#pragma unroll
      for (int q = 0; q < 4; ++q)
        gxv[q] = bf2f(gxp[((size_t)(t + 1) * 4 + q) * (size_t)HL]);
    }

    group_barrier(ctr, nblk * (unsigned)(t0 + t + 1));
  }
  cbuf[(size_t)bb * HCAT + hcol] = c;
}

__global__ __launch_bounds__(256, 2) void k_lstm(
    const float* __restrict__ Whh0, const float* __restrict__ Whh1,
    const float* __restrict__ Whh2,
    const ushort_t* __restrict__ gx0, const ushort_t* __restrict__ gx1,
    const ushort_t* __restrict__ gx2,
    ushort_t* __restrict__ hbuf, float* __restrict__ cbuf,
    ushort_t* __restrict__ hs,
    unsigned* __restrict__ bar,        // 24 counters, 128B apart
    int t0, int TC)
{
  __shared__ float gbuf[4][16][17];
  const int g    = blockIdx.x & 7;
  const int rank = blockIdx.x >> 3;
  if (rank < 32) {
    lstm_body<512>(Whh0, gx0, hbuf, cbuf, hs, gbuf, bar + (g * 3 + 0) * 32, 32u,
                   g, rank * 16, 0, t0, TC);
  } else if (rank < 48) {
    lstm_body<256>(Whh1, gx1, hbuf, cbuf, hs, gbuf, bar + (g * 3 + 1) * 32, 16u,
                   g, (rank - 32) * 16, 512, t0, TC);
  } else {
    lstm_body<256>(Whh2, gx2, hbuf, cbuf, hs, gbuf, bar + (g * 3 + 2) * 32, 16u,
                   g, (rank - 48) * 16, 768, t0, TC);
  }
}

// fallback if workspace is too small: distinctive sentinel
__global__ void k_fill(float* __restrict__ out, int n, float v) {
  int i = blockIdx.x * 256 + threadIdx.x;
  if (i < n) out[i] = v;
}

extern "C" void kernel_launch(void* const* d_in, const int* in_sizes, int n_in,
                              void* d_out, int out_size, void* d_ws, size_t ws_size,
                              hipStream_t stream) {
  (void)in_sizes; (void)n_in;
  const float* x0  = (const float*)d_in[0];
  const float* x1  = (const float*)d_in[1];
  const float* x2  = (const float*)d_in[2];
  const float* Wih0 = (const float*)d_in[3];
  const float* Whh0 = (const float*)d_in[4];
  const float* bih0 = (const float*)d_in[5];
  const float* bhh0 = (const float*)d_in[6];
  const float* Wih1 = (const float*)d_in[7];
  const float* Whh1 = (const float*)d_in[8];
  const float* bih1 = (const float*)d_in[9];
  const float* bhh1 = (const float*)d_in[10];
  const float* Wih2 = (const float*)d_in[11];
  const float* Whh2 = (const float*)d_in[12];
  const float* bih2 = (const float*)d_in[13];
  const float* bhh2 = (const float*)d_in[14];
  const float* W1 = (const float*)d_in[15];
  const float* b1 = (const float*)d_in[16];
  const float* W2 = (const float*)d_in[17];
  const float* b2 = (const float*)d_in[18];
  float* out = (float*)d_out;

  // pick largest even chunk TC that fits in ws
  const int cands[6] = {256, 128, 64, 32, 16, 8};
  int TC = 0;
  for (int ci = 0; ci < 6; ++ci) {
    int tc = cands[ci];
    size_t rows = (size_t)NB * tc;
    size_t o = 0;
    auto al = [&](size_t bytes) { o += (bytes + 255) & ~(size_t)255; };
    al(24 * 32 * sizeof(unsigned));     // bar
    al((size_t)2 * NB * HCAT * 2);      // hbuf (bf16)
    al((size_t)NB * HCAT * 4);          // cbuf (fp32)
    al(rows * HCAT * 2);                // hs chunk
    al(rows * 256 * 4);                 // z chunk
    al(rows * 2048 * 2);                // gx0 chunk
    al(rows * 1024 * 2);                // gx1 chunk
    al(rows * 1024 * 2);                // gx2 chunk
    if (o <= ws_size) { TC = tc; break; }
  }
  if (TC == 0) {
    k_fill<<<dim3((out_size + 255) / 256), dim3(256), 0, stream>>>(out, out_size, -8888.f);
    return;
  }
  const int tcShift = __builtin_ctz(TC);
  const size_t rows = (size_t)NB * TC;

  char* ws = (char*)d_ws;
  size_t off = 0;
  auto alloc = [&](size_t bytes) -> void* {
    void* p = ws + off;
    off += (bytes + 255) & ~(size_t)255;
    return p;
  };
  unsigned* bar  = (unsigned*)alloc(24 * 32 * sizeof(unsigned));
  ushort_t* hbuf = (ushort_t*)alloc((size_t)2 * NB * HCAT * 2);
  float* cbuf    = (float*)alloc((size_t)NB * HCAT * 4);
  size_t staticEnd = off;
  ushort_t* hs   = (ushort_t*)alloc(rows * HCAT * 2);
  float* z       = (float*)alloc(rows * 256 * 4);
  bf16* gx0      = (bf16*)alloc(rows * 2048 * 2);
  bf16* gx1      = (bf16*)alloc(rows * 1024 * 2);
  bf16* gx2      = (bf16*)alloc(rows * 1024 * 2);

  // zero bar + hbuf + cbuf (h0 = c0 = 0)
  hipMemsetAsync(ws, 0, staticEnd, stream);

  dim3 blk(256);
  const int rb = (int)(rows / 64);   // row-blocks per chunk
  for (int t0 = 0; t0 < NT; t0 += TC) {
    k_gx<<<dim3(rb, 2048 / 64), blk, 0, stream>>>(x0, Wih0, bih0, bhh0, gx0, 300, 2048, t0, tcShift);
    k_gx<<<dim3(rb, 1024 / 64), blk, 0, stream>>>(x1, Wih1, bih1, bhh1, gx1, 74, 1024, t0, tcShift);
    k_gx<<<dim3(rb, 1024 / 64), blk, 0, stream>>>(x2, Wih2, bih2, bhh2, gx2, 35, 1024, t0, tcShift);

    k_lstm<<<dim3(512), blk, 0, stream>>>(Whh0, Whh1, Whh2,
                                          (const ushort_t*)gx0, (const ushort_t*)gx1,
                                          (const ushort_t*)gx2,
                                          hbuf, cbuf, hs, bar, t0, TC);

    k_fc1<<<dim3(rb, 256 / 64), blk, 0, stream>>>((const bf16*)hs, W1, b1, z);
    k_fc2<<<dim3((int)(rows / 4)), blk, 0, stream>>>(z, W2, b2, out, t0, tcShift);
  }
}